// Round 2
// baseline (194.095 us; speedup 1.0000x reference)
//
#include <hip/hip_runtime.h>

// AWGN index channel: rx = idx XOR bitflip-mask(u < BER), codebook gather,
// concat [fine | coarse] per batch row. Exact integer semantics -> absmax 0.
//
// R5 (= R4 + compile fix): gather de-latency. The timed region carries a
// fixed ~99.5us harness poison fill; of the controllable ~86us, the gather
// (~80us, 2.1 TB/s on a 168 MB write stream) is latency-chain-bound, not
// BW-bound:
//   rx L2-load -> cb L2-load -> store, only 2 chains in flight (unroll 2),
//   and the output stream's L2 write-allocate evicts the codebooks.
// Fixes: (a) stage the block's 160 rx values in LDS once, copy to registers
// (rx leaves the per-iteration chain entirely); (b) full unroll -> 20
// independent cb loads per thread (MLP ~20); (c) nontemporal stores keep
// codebooks L2-resident. Fine/coarse split is iteration-uniform
// (NF/(8*GRID) = 16), so the loop splits into two branch-free loops.
// NOTE: __builtin_nontemporal_store requires a NATIVE vector type ->
// use ext_vector_type(4) alias, not HIP's float4 class.

typedef float f4 __attribute__((ext_vector_type(4)));

constexpr int   BITS       = 9;
constexpr float BER        = 0.02f;
constexpr int   Bn         = 64;
constexpr int   HC = 32, WC = 32, HF = 64, WF = 64, D = 128;
constexpr int   NF         = Bn * HF * WF;     // 262144 fine symbols
constexpr int   NC         = Bn * HC * WC;     // 65536 coarse symbols
constexpr int   NTOT       = NF + NC;          // 327680
constexpr int   FINE_ROW   = HF * WF * D;      // 524288 floats
constexpr int   COARSE_ROW = HC * WC * D;      // 131072 floats
constexpr int   ROW        = FINE_ROW + COARSE_ROW; // 655360 floats / batch row

// ---------------- Kernel A: bit-flip channel -> rx indices ----------------
// One thread per symbol. NF = 1024 blocks exactly, so the fine/coarse branch
// is block-uniform. 9 scalar loads per thread (36 B span), all 64 lanes
// active. Traffic: 11.8 MB read + 1.3 MB write. ~5us; not the target.
__global__ __launch_bounds__(256) void flip_kernel(
    const int*   __restrict__ idx_c,
    const int*   __restrict__ idx_f,
    const float* __restrict__ u_c,
    const float* __restrict__ u_f,
    int*         __restrict__ rx)
{
    const int s = blockIdx.x * 256 + threadIdx.x;   // [0, NTOT)
    const float* u;  const int* idxp;  int local;
    if (s < NF) { u = u_f; idxp = idx_f; local = s; }
    else        { u = u_c; idxp = idx_c; local = s - NF; }
    const float* up = u + (size_t)local * BITS;
    int flip = 0;
    #pragma unroll
    for (int k = 0; k < BITS; ++k)
        flip |= (up[k] < BER) ? (1 << k) : 0;
    rx[s] = (idxp[local] ^ flip) & 511;             // clip is a no-op
}

// ---------------- Kernel B: codebook gather + concat store ----------------
// Half-wave (32 lanes x float4 = 512 B) per symbol; wave stores 1 KB
// contiguous, block 4 KB per iteration. Chunks of 8 symbols are purely fine
// or purely coarse (NF % 8 == 0), and with GRID=2048 the fine/coarse
// boundary falls exactly at iteration 16 for every block.
constexpr int GRID       = 2048;                    // 8 blocks/CU
constexpr int ITERS      = NTOT / (8 * GRID);       // 20, exact
constexpr int FINE_ITERS = NF   / (8 * GRID);       // 16, exact

__global__ __launch_bounds__(256) void gather_kernel(
    const float* __restrict__ cb_c,
    const float* __restrict__ cb_f,
    const int*   __restrict__ rx,
    float*       __restrict__ out)
{
    __shared__ int srow[ITERS * 8];                 // 640 B

    const int t = threadIdx.x;

    // Stage this block's 160 rx values (20 chunks of 8, stride GRID*8) once.
    if (t < ITERS * 8) {
        const int chunk = (t >> 3) * GRID + blockIdx.x;
        srow[t] = rx[chunk * 8 + (t & 7)];
    }
    __syncthreads();

    const int sym  = t >> 5;                        // 0..7
    const int lane = t & 31;                        // float4 slot in 128-f row

    // Rows to registers: every cb load below is independent -> deep MLP.
    int row[ITERS];
    #pragma unroll
    for (int k = 0; k < ITERS; ++k)
        row[k] = srow[k * 8 + sym];                 // broadcast LDS read

    const int base = blockIdx.x * 8 + sym;          // i = it*(GRID*8) + base

    // Fine iterations: all blocks, it in [0,16).
    #pragma unroll
    for (int it = 0; it < FINE_ITERS; ++it) {
        const int i   = it * (GRID * 8) + base;
        const int b   = i >> 12;                    // / (HF*WF)
        const int rem = i & 4095;                   // % (HF*WF)
        const f4 v = ((const f4*)(cb_f + row[it] * D))[lane];  // L2 hit
        __builtin_nontemporal_store(
            v, (f4*)(out + b * ROW + rem * D) + lane);  // 512 B contig/sym
    }

    // Coarse iterations: all blocks, it in [16,20).
    #pragma unroll
    for (int it = FINE_ITERS; it < ITERS; ++it) {
        const int j   = it * (GRID * 8) + base - NF;
        const int b   = j >> 10;                    // / (HC*WC)
        const int rem = j & 1023;                   // % (HC*WC)
        const f4 v = ((const f4*)(cb_c + row[it] * D))[lane];  // L2 hit
        __builtin_nontemporal_store(
            v, (f4*)(out + b * ROW + FINE_ROW + rem * D) + lane);
    }
}

extern "C" void kernel_launch(void* const* d_in, const int* in_sizes, int n_in,
                              void* d_out, int out_size, void* d_ws, size_t ws_size,
                              hipStream_t stream) {
    const int*   idx_c = (const int*)  d_in[0];
    const int*   idx_f = (const int*)  d_in[1];
    const float* cb_c  = (const float*)d_in[2];
    const float* cb_f  = (const float*)d_in[3];
    const float* u_c   = (const float*)d_in[4];
    const float* u_f   = (const float*)d_in[5];
    float*       out   = (float*)d_out;
    int*         rx    = (int*)d_ws;                // 1.3 MB of scratch

    flip_kernel<<<NTOT / 256, 256, 0, stream>>>(idx_c, idx_f, u_c, u_f, rx);
    gather_kernel<<<GRID, 256, 0, stream>>>(cb_c, cb_f, rx, out);
}

// Round 3
// 183.472 us; speedup vs baseline: 1.0579x; 1.0579x over previous
//
#include <hip/hip_runtime.h>

// AWGN index channel: rx = idx XOR bitflip-mask(u < BER), codebook gather,
// concat [fine | coarse] per batch row. Exact integer semantics -> absmax 0.
//
// R6: single fused kernel. R5 post-mortem: 20-deep MLP + NT stores were
// exactly neutral after clock normalization vs unroll-2 -- the gather is NOT
// latency-chain-bound and NOT codebook-eviction-bound. Remaining suspects:
// two-dispatch structure cost (launch gap + 2.6 MB rx round-trip) vs an
// already-reached harness floor (~100us poison fill + write roofline).
// This round removes the structure cost entirely:
//  - one kernel; block b owns the contiguous symbol range [160b, 160b+160)
//  - phase 1: threads 0..159 compute rx inline (9 contiguous u floats each,
//    5.76 KB/block fully coalesced) -> LDS. No global rx traffic at all.
//  - phase 2: gather exactly as before, but per-block output is 80 KB
//    sequential (4 KB contiguous per iteration) -- third distinct write
//    pattern tried; matches per-block-chunk streaming.
// Normal (temporal) stores: NT measured neutral, and 168 MB output fits L3.
// If this round is again clock-normalized-neutral, the floor is structural.

typedef float f4 __attribute__((ext_vector_type(4)));

constexpr int   BITS       = 9;
constexpr float BER        = 0.02f;
constexpr int   Bn         = 64;
constexpr int   HC = 32, WC = 32, HF = 64, WF = 64, D = 128;
constexpr int   NF         = Bn * HF * WF;     // 262144 fine symbols
constexpr int   NC         = Bn * HC * WC;     // 65536 coarse symbols
constexpr int   NTOT       = NF + NC;          // 327680
constexpr int   FINE_ROW   = HF * WF * D;      // 524288 floats
constexpr int   COARSE_ROW = HC * WC * D;      // 131072 floats
constexpr int   ROW        = FINE_ROW + COARSE_ROW; // 655360 floats / batch row

constexpr int   GRID  = 2048;                  // 8 blocks/CU
constexpr int   SPB   = NTOT / GRID;           // 160 symbols per block, exact
constexpr int   ITERS = SPB / 8;               // 20 store iterations

__global__ __launch_bounds__(256) void fused_kernel(
    const int*   __restrict__ idx_c,
    const int*   __restrict__ idx_f,
    const float* __restrict__ cb_c,
    const float* __restrict__ cb_f,
    const float* __restrict__ u_c,
    const float* __restrict__ u_f,
    float*       __restrict__ out)
{
    __shared__ int srow[SPB];                   // 640 B

    const int t  = threadIdx.x;
    const int s0 = blockIdx.x * SPB;            // first symbol of this block

    // ---- Phase 1: bit-flip channel for this block's 160 symbols -> LDS ----
    // Thread t handles symbol s0+t. u reads are 36 B/thread, contiguous
    // across the block (5.76 KB). Only block 1638 mixes fine/coarse
    // (NF/SPB = 1638.4); branch is half-wave-uniform elsewhere.
    if (t < SPB) {
        const int i = s0 + t;
        const float* up;  const int* idxp;  int local;
        if (i < NF) { local = i;      up = u_f + (size_t)local * BITS; idxp = idx_f; }
        else        { local = i - NF; up = u_c + (size_t)local * BITS; idxp = idx_c; }
        int flip = 0;
        #pragma unroll
        for (int k = 0; k < BITS; ++k)
            flip |= (up[k] < BER) ? (1 << k) : 0;
        srow[t] = (idxp[local] ^ flip) & 511;   // clip is a no-op
    }
    __syncthreads();

    // ---- Phase 2: codebook gather + concat store ----
    // Half-wave (32 lanes x float4 = 512 B) per symbol; block writes 4 KB
    // contiguous per iteration, 80 KB sequential overall.
    const int sym  = t >> 5;                    // 0..7
    const int lane = t & 31;                    // float4 slot in 128-f row

    int row[ITERS];
    #pragma unroll
    for (int k = 0; k < ITERS; ++k)
        row[k] = srow[k * 8 + sym];             // 2 distinct addrs/wave: bcast

    #pragma unroll 4
    for (int it = 0; it < ITERS; ++it) {
        const int i = s0 + it * 8 + sym;        // half-wave-uniform
        const float* src;  int off;
        if (i < NF) {
            const int b = i >> 12, rem = i & 4095;   // / , % (HF*WF)
            src = cb_f + row[it] * D;
            off = b * ROW + rem * D;
        } else {
            const int j = i - NF;
            const int b = j >> 10, rem = j & 1023;   // / , % (HC*WC)
            src = cb_c + row[it] * D;
            off = b * ROW + FINE_ROW + rem * D;
        }
        const f4 v = ((const f4*)src)[lane];    // 512 B/symbol, L2-resident
        ((f4*)(out + off))[lane] = v;           // 512 B contiguous/symbol
    }
}

extern "C" void kernel_launch(void* const* d_in, const int* in_sizes, int n_in,
                              void* d_out, int out_size, void* d_ws, size_t ws_size,
                              hipStream_t stream) {
    const int*   idx_c = (const int*)  d_in[0];
    const int*   idx_f = (const int*)  d_in[1];
    const float* cb_c  = (const float*)d_in[2];
    const float* cb_f  = (const float*)d_in[3];
    const float* u_c   = (const float*)d_in[4];
    const float* u_f   = (const float*)d_in[5];
    float*       out   = (float*)d_out;
    (void)d_ws; (void)ws_size;                  // no workspace needed anymore

    fused_kernel<<<GRID, 256, 0, stream>>>(idx_c, idx_f, cb_c, cb_f, u_c, u_f, out);
}